// Round 11
// baseline (1325.685 us; speedup 1.0000x reference)
//
#include <hip/hip_runtime.h>

// DecoderCell v11: faithful m201-style 256x256 8-phase GEMM (1 block/CU,
// 8 waves of 128x64, 16-MFMA phases, frag reuse, setprio, counted staging)
// for the 4 big GEMMs. All operand buffers stored PRE-TILED as
// [rowtile(128)][ktile(64)] 16KB blocks with slot^(row&7) swizzle:
// staging = linear 1KB copies, ds_read_b128 conflict-free.
//
// h_0 layout: [gen 0:512 | con 512:768 | mean 768:832 | std 832:896 | gi 896:960 | factor 960:1088]
// A_con[32768][640] = [input 256 | factor 128 | h_con->hnew_con 256]  (tiled)
// A_gen[32768][576] = [gi 64 | h_gen->hnew_gen 512]                   (tiled)

typedef short  s16x8 __attribute__((ext_vector_type(8)));
typedef float  f32x4 __attribute__((ext_vector_type(4)));
typedef unsigned short ush;

#define OUTP 1088
#define NROW 32768

// tiled+swizzled index: [row>>7][col>>6] 8192-ush blocks; within:
// [row&127][ ((col>>3)&7) ^ (row&7) ][col&7]
__device__ __forceinline__ size_t tix(int nkt, int row, int col) {
  return ((((size_t)(row >> 7) * nkt + (col >> 6)) << 7) + (row & 127)) * 64
         + ((((col >> 3) & 7) ^ (row & 7)) << 3) + (col & 7);
}
__device__ __forceinline__ ush f2bf(float f) {
  union { float f; unsigned int u; } v; v.f = f;
  unsigned int u = v.u;
  return (ush)((u + 0x7FFFu + ((u >> 16) & 1u)) >> 16);  // RNE
}
__device__ __forceinline__ float bf2f(ush b) {
  union { unsigned int u; float f; } v; v.u = ((unsigned int)b) << 16;
  return v.f;
}
__device__ __forceinline__ float sigm(float x) { return 1.f / (1.f + __expf(-x)); }
__device__ __forceinline__ float tanh_(float x) { return 2.f / (1.f + __expf(-2.f * x)) - 1.f; }
__device__ __forceinline__ f32x4 mfma16(s16x8 a, s16x8 b, f32x4 c) {
  return __builtin_amdgcn_mfma_f32_16x16x32_bf16(a, b, c, 0, 0, 0);
}
__device__ __forceinline__ s16x8 ldb8(const ush* p) {
  return *reinterpret_cast<const s16x8*>(p);
}
__device__ __forceinline__ void gld16(const ush* g, ush* l) {
  __builtin_amdgcn_global_load_lds(
      (const __attribute__((address_space(1))) unsigned int*)g,
      (__attribute__((address_space(3))) unsigned int*)l, 16, 0, 0);
}
__device__ __forceinline__ ushort4 pack4(float4 a) {
  ushort4 o; o.x = f2bf(a.x); o.y = f2bf(a.y); o.z = f2bf(a.z); o.w = f2bf(a.w);
  return o;
}
__device__ __forceinline__ void store8(ush* base, size_t ix, float4 a, float4 b) {
  *reinterpret_cast<ushort4*>(&base[ix]) = pack4(a);
  *reinterpret_cast<ushort4*>(&base[ix + 4]) = pack4(b);
}

// ---- prep: A_con + A_gen h-sections, bf16 tiled ----------------------------
__global__ void prepA_kernel(const float* __restrict__ in, const float* __restrict__ h0,
                             ush* __restrict__ Acon, ush* __restrict__ Agen) {
  int t = blockIdx.x * 256 + threadIdx.x;      // 32768 * 144
  int row = t / 144, c = t % 144;
  if (c < 80) {
    int c8 = c * 8;
    const float* src;
    if (c8 < 256)      src = &in[(size_t)row * 256 + c8];
    else if (c8 < 384) src = &h0[(size_t)row * OUTP + 960 + (c8 - 256)];
    else               src = &h0[(size_t)row * OUTP + 512 + (c8 - 384)];
    store8(Acon, tix(10, row, c8),
           *reinterpret_cast<const float4*>(src),
           *reinterpret_cast<const float4*>(src + 4));
  } else {
    int c8 = (c - 80) * 8;
    const float* src = &h0[(size_t)row * OUTP + c8];
    store8(Agen, tix(9, row, 64 + c8),
           *reinterpret_cast<const float4*>(src),
           *reinterpret_cast<const float4*>(src + 4));
  }
}

// ---- prep: con weights -> [Wih(384)|Whh(256)] tiled ------------------------
__global__ void packBcon_kernel(const float* __restrict__ wih, const float* __restrict__ whh,
                                ush* __restrict__ B1, ush* __restrict__ B2) {
  int r = blockIdx.x;            // 0..767
  int c8 = threadIdx.x * 8;      // 80 threads
  const float* s = (c8 < 384) ? &wih[(size_t)r * 384 + c8]
                              : &whh[(size_t)r * 256 + (c8 - 384)];
  float4 a = *reinterpret_cast<const float4*>(s);
  float4 b = *reinterpret_cast<const float4*>(s + 4);
  if (r < 512) store8(B1, tix(10, r, c8), a, b);
  else         store8(B2, tix(10, r - 512, c8), a, b);
}

// ---- prep: gen weights -> [Wih(64)|Whh(512)] tiled -------------------------
__global__ void packBgen_kernel(const float* __restrict__ wih, const float* __restrict__ whh,
                                ush* __restrict__ B1, ush* __restrict__ B2) {
  int r = blockIdx.x;            // 0..1535
  int c8 = threadIdx.x * 8;      // 72 threads
  const float* s = (c8 < 64) ? &wih[(size_t)r * 64 + c8]
                             : &whh[(size_t)r * 512 + (c8 - 64)];
  float4 a = *reinterpret_cast<const float4*>(s);
  float4 b = *reinterpret_cast<const float4*>(s + 4);
  if (r < 1024) store8(B1, tix(9, r, c8), a, b);
  else          store8(B2, tix(9, r - 1024, c8), a, b);
}

// ---- prep: co_W (128x256) tiled --------------------------------------------
__global__ void cvtco_kernel(const float* __restrict__ src, ush* __restrict__ dst) {
  int row = blockIdx.x, c8 = threadIdx.x * 8;   // 128 x 32
  const float* s = &src[(size_t)row * 256 + c8];
  store8(dst, tix(4, row, c8),
         *reinterpret_cast<const float4*>(s), *reinterpret_cast<const float4*>(s + 4));
}

// ---- prep: row-L2-normalize fac_W (128x512) tiled --------------------------
__global__ void facnorm_kernel(const float* __restrict__ w, ush* __restrict__ dst) {
  int row = blockIdx.x, lane = threadIdx.x;     // 128 x 64
  float v[8]; float s = 0.f;
  #pragma unroll
  for (int i = 0; i < 8; ++i) { v[i] = w[row * 512 + lane * 8 + i]; s += v[i] * v[i]; }
  #pragma unroll
  for (int off = 32; off; off >>= 1) s += __shfl_xor(s, off);
  float scale = 1.f / fmaxf(sqrtf(s), 1e-12f);
  size_t ix = tix(8, row, lane * 8);
  #pragma unroll
  for (int i = 0; i < 8; ++i) dst[ix + i] = f2bf(v[i] * scale);
}

// ---- rsample: gi = mean + std*eps -> out + A_gen (tiled) -------------------
__global__ void rsample_kernel(const float* __restrict__ eps, float* __restrict__ out,
                               ush* __restrict__ Agen) {
  int t = blockIdx.x * 256 + threadIdx.x;      // 32768*64
  int m = t >> 6, j = t & 63;
  float mean = out[(size_t)m * OUTP + 768 + j];
  float sd   = out[(size_t)m * OUTP + 832 + j];
  float g = mean + sd * eps[(size_t)m * 64 + j];
  out[(size_t)m * OUTP + 896 + j] = g;
  Agen[tix(9, m, j)] = f2bf(g);
}

#define MM(MH, NH, BF)                                                        \
  { _Pragma("unroll") for (int i = 0; i < 4; ++i)                             \
      _Pragma("unroll") for (int j = 0; j < 2; ++j)                           \
        _Pragma("unroll") for (int kk = 0; kk < 2; ++kk)                      \
          acc[(MH)*4+i][(NH)*2+j] =                                           \
              mfma16(af[i*2+kk], BF[j*2+kk], acc[(MH)*4+i][(NH)*2+j]); }

// ---- WIDE GEMM: 256x256 tile, BK=64, 8 waves of 128x64, 4 big phases/tile --
// EPI 0 = zr-gate (z->st1 linear, rh->st2 tiled), 1 = n-gate (hnew->st1 tiled
// + out f32).
template<int EPI, int NK, int KA1T, int A1NKT, int A2NKT, int A1OFS,
         int BNKT, int NT, int NHALF, int AHNKT, int AHCOFS, int OOFS>
__global__ __launch_bounds__(512, 1) void gemmw_kernel(
    const ush* __restrict__ A1, const ush* __restrict__ A2,
    const ush* __restrict__ B,
    const float* __restrict__ bih, const float* __restrict__ bhh,
    const ush* __restrict__ Ah, const ush* __restrict__ zbuf,
    ush* __restrict__ st1, ush* __restrict__ st2,
    float* __restrict__ out)
{
  __shared__ __align__(16) ush S[2 * 32768];   // 128 KB: [buf][A0|A1|B0|B1]
  const int nwg = gridDim.x;
  const int wg = (blockIdx.x & 7) * (nwg >> 3) + (blockIdx.x >> 3);
  const int mt = wg / NT, nt = wg % NT;
  const int m0 = mt * 256, n0 = nt * 256;
  const int rt0 = mt * 2, bt0 = nt * 2;
  const int tid = threadIdx.x;
  const int wv = tid >> 6, lane = tid & 63;
  const int ln = lane & 15, lk = lane >> 4;
  const int wm = wv >> 2, wn = wv & 3;   // 2M x 4N, wave = 128x64

  f32x4 acc[8][4] = {};
  s16x8 af[8], bfA[4], bfB[4];

  auto stage_half = [&](int p, int kt1, int buf) {
    ush* dstb = &S[buf * 32768];
    const ush* srcblk; ush* dst;
    if ((p & 1) == 0) {                  // A half p>>1
      int mh = p >> 1;
      const ush* base; int nkt, kti;
      if (kt1 < KA1T) { base = A1; nkt = A1NKT; kti = A1OFS + kt1; }
      else            { base = A2; nkt = A2NKT; kti = kt1 - KA1T; }
      srcblk = base + (((size_t)(rt0 + mh) * nkt + kti) << 13);
      dst = dstb + mh * 8192;
    } else {                             // B half p>>1
      int bh = p >> 1;
      srcblk = B + (((size_t)(bt0 + bh) * BNKT + kt1) << 13);
      dst = dstb + 16384 + bh * 8192;
    }
    #pragma unroll
    for (int l = 0; l < 2; ++l) {
      int ch = wv * 2 + l;
      gld16(srcblk + ch * 512 + lane * 8, dst + ch * 512);
    }
  };
  auto lda = [&](int mh, const ush* Asw) {
    #pragma unroll
    for (int i = 0; i < 4; ++i)
      #pragma unroll
      for (int kk = 0; kk < 2; ++kk) {
        int r = mh * 64 + i * 16 + ln;
        af[i * 2 + kk] = ldb8(&Asw[r * 64 + (((kk * 4 + lk) ^ (ln & 7)) << 3)]);
      }
  };
  auto ldbv = [&](s16x8* bf, int nh, const ush* Bsw) {
    #pragma unroll
    for (int j = 0; j < 2; ++j)
      #pragma unroll
      for (int kk = 0; kk < 2; ++kk) {
        int r = (wn & 1) * 64 + nh * 32 + j * 16 + ln;
        bf[j * 2 + kk] = ldb8(&Bsw[r * 64 + (((kk * 4 + lk) ^ (ln & 7)) << 3)]);
      }
  };

  // prologue: stage tile 0 into buf 0
  stage_half(0, 0, 0); stage_half(1, 0, 0);
  stage_half(2, 0, 0); stage_half(3, 0, 0);

  for (int kt = 0; kt < NK; ++kt) {
    const int cur = kt & 1;
    asm volatile("s_waitcnt vmcnt(0)" ::: "memory");
    __builtin_amdgcn_s_barrier();
    const ush* Asw = &S[cur * 32768 + wm * 8192];
    const ush* Bsw = &S[cur * 32768 + 16384 + (wn >> 1) * 8192];
    const bool st = (kt + 1 < NK);
    // phase 0: (mh0, nh0)
    lda(0, Asw); ldbv(bfA, 0, Bsw);
    if (st) stage_half(0, kt + 1, cur ^ 1);
    __builtin_amdgcn_s_barrier();
    asm volatile("s_waitcnt lgkmcnt(0)" ::: "memory");
    __builtin_amdgcn_sched_barrier(0);
    __builtin_amdgcn_s_setprio(1); MM(0, 0, bfA); __builtin_amdgcn_s_setprio(0);
    __builtin_amdgcn_s_barrier();
    // phase 1: (0,1)
    ldbv(bfB, 1, Bsw);
    if (st) stage_half(1, kt + 1, cur ^ 1);
    __builtin_amdgcn_s_barrier();
    asm volatile("s_waitcnt lgkmcnt(0)" ::: "memory");
    __builtin_amdgcn_sched_barrier(0);
    __builtin_amdgcn_s_setprio(1); MM(0, 1, bfB); __builtin_amdgcn_s_setprio(0);
    __builtin_amdgcn_s_barrier();
    // phase 2: (1,0)
    lda(1, Asw);
    if (st) stage_half(2, kt + 1, cur ^ 1);
    __builtin_amdgcn_s_barrier();
    asm volatile("s_waitcnt lgkmcnt(0)" ::: "memory");
    __builtin_amdgcn_sched_barrier(0);
    __builtin_amdgcn_s_setprio(1); MM(1, 0, bfA); __builtin_amdgcn_s_setprio(0);
    __builtin_amdgcn_s_barrier();
    // phase 3: (1,1)
    if (st) stage_half(3, kt + 1, cur ^ 1);
    __builtin_amdgcn_s_barrier();
    __builtin_amdgcn_s_setprio(1); MM(1, 1, bfB); __builtin_amdgcn_s_setprio(0);
    __builtin_amdgcn_s_barrier();
  }
  __syncthreads();

  // ---- epilogue: two 128-col passes through 256x128 bf16 LDS tile ----------
  ush* Ls = S;
  #pragma unroll
  for (int h = 0; h < 2; ++h) {
    const int cb = n0 + h * 128;
    if ((wn >> 1) == h) {
      #pragma unroll
      for (int mh = 0; mh < 2; ++mh)
        #pragma unroll
        for (int i = 0; i < 4; ++i)
          #pragma unroll
          for (int nh = 0; nh < 2; ++nh)
            #pragma unroll
            for (int j = 0; j < 2; ++j) {
              const int jl = (wn & 1) * 64 + nh * 32 + j * 16 + ln;
              const int jg = cb + jl;
              #pragma unroll
              for (int rr = 0; rr < 4; ++rr) {
                const int rl = wm * 128 + mh * 64 + i * 16 + lk * 4 + rr;
                const size_t m = (size_t)(m0 + rl);
                float v = acc[mh * 4 + i][nh * 2 + j][rr];
                float val;
                if constexpr (EPI == 0) {
                  float bb = bih[jg] + bhh[jg];
                  float sv = sigm(v + bb);
                  if (cb >= NHALF)
                    sv *= bf2f(Ah[tix(AHNKT, m, AHCOFS + (jg - NHALF))]);
                  val = sv;
                } else {
                  float bb = bih[2 * NHALF + jg] + bhh[2 * NHALF + jg];
                  float n = tanh_(v + bb);
                  float z = bf2f(zbuf[m * NHALF + jg]);
                  float hh = bf2f(Ah[tix(AHNKT, m, AHCOFS + jg)]);
                  val = fminf(fmaxf(z * hh + (1.f - z) * n, -5.f), 5.f);
                }
                Ls[rl * 128 + (jl ^ ((rl & 7) << 3))] = f2bf(val);
              }
            }
    }
    __syncthreads();
    #pragma unroll
    for (int q = 0; q < 8; ++q) {
      int idx = q * 512 + tid;
      int r = idx >> 4, c8 = (idx & 15) * 8;
      union { float4 f; ush u[8]; } U;
      U.f = *reinterpret_cast<const float4*>(&Ls[r * 128 + (c8 ^ ((r & 7) << 3))]);
      const size_t m = (size_t)(m0 + r);
      const int col = cb + c8;
      if constexpr (EPI == 0) {
        if (cb < NHALF) *reinterpret_cast<float4*>(&st1[m * NHALF + col]) = U.f;
        else *reinterpret_cast<float4*>(&st2[tix(NHALF >> 6, m, col - NHALF)]) = U.f;
      } else {
        *reinterpret_cast<float4*>(&st1[tix(AHNKT, m, AHCOFS + col)]) = U.f;
        float4 o0 = { bf2f(U.u[0]), bf2f(U.u[1]), bf2f(U.u[2]), bf2f(U.u[3]) };
        float4 o1 = { bf2f(U.u[4]), bf2f(U.u[5]), bf2f(U.u[6]), bf2f(U.u[7]) };
        float* ob = &out[m * OUTP + OOFS + col];
        *reinterpret_cast<float4*>(ob) = o0;
        *reinterpret_cast<float4*>(ob + 4) = o1;
      }
    }
    __syncthreads();
  }
}

// ---- NARROW GEMM: 128x128, 256 thr, single-buf; EPI 2=co, 3=factor ---------
template<int EPI, int NK, int ANKT, int AOFS, int BNKT>
__global__ __launch_bounds__(256, 4) void gemmn_kernel(
    const ush* __restrict__ A, const ush* __restrict__ B,
    const float* __restrict__ bias, float* __restrict__ out)
{
  __shared__ __align__(16) ush S[2 * 8192];   // A | B (32 KB)
  const int nwg = gridDim.x;
  const int wg = (blockIdx.x & 7) * (nwg >> 3) + (blockIdx.x >> 3);
  const int m0 = wg * 128;
  const int tid = threadIdx.x;
  const int wv = tid >> 6, lane = tid & 63;
  const int ln = lane & 15, lk = lane >> 4;
  const int wm = wv >> 1, wn = wv & 1;

  f32x4 acc[4][4] = {};

  for (int kt = 0; kt < NK; ++kt) {
    const ush* ablk = A + (((size_t)(m0 >> 7) * ANKT + AOFS + kt) << 13);
    const ush* bblk = B + (((size_t)kt) << 13);
    #pragma unroll
    for (int l = 0; l < 4; ++l) {
      int ch = wv * 4 + l;
      gld16(ablk + ch * 512 + lane * 8, &S[ch * 512]);
      gld16(bblk + ch * 512 + lane * 8, &S[8192 + ch * 512]);
    }
    asm volatile("s_waitcnt vmcnt(0)" ::: "memory");
    __syncthreads();
    #pragma unroll
    for (int kk = 0; kk < 2; ++kk) {
      s16x8 af[4], bf[4];
      #pragma unroll
      for (int i = 0; i < 4; ++i) {
        int r = wm * 64 + i * 16 + ln;
        af[i] = ldb8(&S[r * 64 + (((kk * 4 + lk) ^ (ln & 7)) << 3)]);
      }
      #pragma unroll
      for (int j = 0; j < 4; ++j) {
        int r = wn * 64 + j * 16 + ln;
        bf[j] = ldb8(&S[8192 + r * 64 + (((kk * 4 + lk) ^ (ln & 7)) << 3)]);
      }
      #pragma unroll
      for (int i = 0; i < 4; ++i)
        #pragma unroll
        for (int j = 0; j < 4; ++j)
          acc[i][j] = mfma16(af[i], bf[j], acc[i][j]);
    }
    __syncthreads();
  }

  #pragma unroll
  for (int i = 0; i < 4; ++i)
    #pragma unroll
    for (int j = 0; j < 4; ++j) {
      const int jg = wn * 64 + j * 16 + ln;
      #pragma unroll
      for (int r = 0; r < 4; ++r) {
        const size_t m = (size_t)(m0 + wm * 64 + i * 16 + lk * 4 + r);
        if constexpr (EPI == 2) {
          float v = acc[i][j][r] + bias[jg];
          if (jg < 64) out[m * OUTP + 768 + jg] = v;
          else         out[m * OUTP + 832 + (jg - 64)] = __expf(0.5f * v);
        } else {
          out[m * OUTP + 960 + jg] = acc[i][j][r];
        }
      }
    }
}

extern "C" void kernel_launch(void* const* d_in, const int* in_sizes, int n_in,
                              void* d_out, int out_size, void* d_ws, size_t ws_size,
                              hipStream_t stream) {
  const float* input   = (const float*)d_in[0];
  const float* h0      = (const float*)d_in[1];
  const float* eps     = (const float*)d_in[2];
  const float* gen_Wih = (const float*)d_in[3];
  const float* gen_bih = (const float*)d_in[4];
  const float* gen_Whh = (const float*)d_in[5];
  const float* gen_bhh = (const float*)d_in[6];
  const float* con_Wih = (const float*)d_in[7];
  const float* con_bih = (const float*)d_in[8];
  const float* con_Whh = (const float*)d_in[9];
  const float* con_bhh = (const float*)d_in[10];
  const float* fac_W   = (const float*)d_in[11];
  const float* co_W    = (const float*)d_in[12];
  const float* co_b    = (const float*)d_in[13];
  float* out = (float*)d_out;

  ush* ws = (ush*)d_ws;
  ush* A_gen  = ws;                                  // 32768*576 (tiled, NKT 9)
  ush* A_con  = A_gen + (size_t)NROW * 576;          // 32768*640 (tiled, NKT 10)
  ush* z_con  = A_con + (size_t)NROW * 640;          // 32768*256 linear
  ush* rh_con = z_con + (size_t)NROW * 256;          // 32768*256 tiled NKT 4
  ush* B1c    = rh_con + (size_t)NROW * 256;         // 512*640 tiled NKT 10
  ush* B2c    = B1c + 512 * 640;                     // 256*640 tiled NKT 10
  ush* B1g    = B2c + 256 * 640;                     // 1024*576 tiled NKT 9
  ush* B2g    = B1g + 1024 * 576;                    // 512*576 tiled NKT 9
  ush* coWb   = B2g + 512 * 576;                     // 128*256 tiled NKT 4
  ush* facWn  = coWb + 128 * 256;                    // 128*512 tiled NKT 8
  // aliases over dead con-phase buffers (gen phase runs after co/rsample):
  ush* z_gen  = A_con;                               // linear 32768*512
  ush* rh_gen = z_con;                               // tiled NKT 8 (16.78M ush)

  // ---- prep ----
  packBcon_kernel<<<768, 80, 0, stream>>>(con_Wih, con_Whh, B1c, B2c);
  packBgen_kernel<<<1536, 72, 0, stream>>>(gen_Wih, gen_Whh, B1g, B2g);
  cvtco_kernel<<<128, 32, 0, stream>>>(co_W, coWb);
  facnorm_kernel<<<128, 64, 0, stream>>>(fac_W, facWn);
  prepA_kernel<<<18432, 256, 0, stream>>>(input, h0, A_con, A_gen);

  // ---- controller ----
  // zr: K=640 (10kt), N=512 -> NT=2, grid 128*2
  gemmw_kernel<0, 10, 99, 10, 10, 0, 10, 2, 256, 10, 384, 0>
      <<<256, 512, 0, stream>>>(A_con, A_con, B1c, con_bih, con_bhh,
                                A_con, nullptr, z_con, rh_con, out);
  // n: K=640, A = [A_con kt0..5 | rh_con kt0..3], N=256 -> NT=1, grid 128
  gemmw_kernel<1, 10, 6, 10, 4, 0, 10, 1, 256, 10, 384, 512>
      <<<128, 512, 0, stream>>>(A_con, rh_con, B2c, con_bih, con_bhh,
                                A_con, z_con, A_con, nullptr, out);
  // co: K=256 over hnew_con (A_con kt6..9)
  gemmn_kernel<2, 4, 10, 6, 4><<<256, 256, 0, stream>>>(A_con, coWb, co_b, out);
  rsample_kernel<<<8192, 256, 0, stream>>>(eps, out, A_gen);

  // ---- generator ----
  // zr: K=576 (9kt), N=1024 -> NT=4, grid 128*4
  gemmw_kernel<0, 9, 99, 9, 9, 0, 9, 4, 512, 9, 64, 0>
      <<<512, 512, 0, stream>>>(A_gen, A_gen, B1g, gen_bih, gen_bhh,
                                A_gen, nullptr, z_gen, rh_gen, out);
  // n: K=576, A = [A_gen kt0 | rh_gen kt0..7], N=512 -> NT=2, grid 256
  gemmw_kernel<1, 9, 1, 9, 8, 0, 9, 2, 512, 9, 64, 0>
      <<<256, 512, 0, stream>>>(A_gen, rh_gen, B2g, gen_bih, gen_bhh,
                                A_gen, z_gen, A_gen, nullptr, out);
  // factor: K=512 over hnew_gen (A_gen kt1..8)
  gemmn_kernel<3, 8, 9, 1, 8><<<256, 256, 0, stream>>>(A_gen, facWn, gen_bih, out);
}

// Round 12
// 550.453 us; speedup vs baseline: 2.4084x; 2.4084x over previous
//
#include <hip/hip_runtime.h>

// DecoderCell v12: v9's proven coarse dbuf pipeline (stage-all -> vmcnt(8) ->
// 2 barriers/K-tile, both-sides XOR swizzle, setprio) with m201 GEOMETRY for
// the 4 big GEMMs: 256x256 tile, 8 waves of 128x64 (0.375 ds_reads/MFMA vs
// v9's 0.75 -> LDS-read pressure halved), 2x64KB LDS, 1 block/CU.
// co/factor keep the v6 narrow kernel. All ws layouts identical to v9.
//
// h_0 layout: [gen 0:512 | con 512:768 | mean 768:832 | std 832:896 | gi 896:960 | factor 960:1088]
// A_con[32768][640] = [input 256 | factor 128 | h_con->hnew_con 256]  (swizzled)
// A_gen[32768][576] = [gi 64 | h_gen->hnew_gen 512]                   (swizzled)

typedef short  s16x8 __attribute__((ext_vector_type(8)));
typedef float  f32x4 __attribute__((ext_vector_type(4)));
typedef unsigned short ush;

#define OUTP 1088
#define NROW 32768

__device__ __forceinline__ int swz(int k, int row) {
  return (k & ~63) | ((k & 63) ^ ((row & 7) << 3));
}
__device__ __forceinline__ ush f2bf(float f) {
  union { float f; unsigned int u; } v; v.f = f;
  unsigned int u = v.u;
  return (ush)((u + 0x7FFFu + ((u >> 16) & 1u)) >> 16);  // RNE
}
__device__ __forceinline__ float bf2f(ush b) {
  union { unsigned int u; float f; } v; v.u = ((unsigned int)b) << 16;
  return v.f;
}
__device__ __forceinline__ float sigm(float x) { return 1.f / (1.f + __expf(-x)); }
__device__ __forceinline__ float tanh_(float x) { return 2.f / (1.f + __expf(-2.f * x)) - 1.f; }

__device__ __forceinline__ f32x4 mfma16(s16x8 a, s16x8 b, f32x4 c) {
  return __builtin_amdgcn_mfma_f32_16x16x32_bf16(a, b, c, 0, 0, 0);
}
__device__ __forceinline__ s16x8 ldb8(const ush* p) {
  return *reinterpret_cast<const s16x8*>(p);
}
__device__ __forceinline__ void gld16(const ush* g, ush* l) {
  __builtin_amdgcn_global_load_lds(
      (const __attribute__((address_space(1))) unsigned int*)g,
      (__attribute__((address_space(3))) unsigned int*)l, 16, 0, 0);
}
__device__ __forceinline__ ushort4 pack4(float4 a) {
  ushort4 o; o.x = f2bf(a.x); o.y = f2bf(a.y); o.z = f2bf(a.z); o.w = f2bf(a.w);
  return o;
}

// ---- prep: A_con = [input|factor|h_con] + A_gen h-section, bf16 swizzled ---
__global__ void prepA_kernel(const float* __restrict__ in, const float* __restrict__ h0,
                             ush* __restrict__ Acon, ush* __restrict__ Agen) {
  int t = blockIdx.x * 256 + threadIdx.x;      // 32768 * 144
  int row = t / 144, c = t % 144;
  if (c < 80) {
    int c8 = c * 8;
    const float* src;
    if (c8 < 256)      src = &in[(size_t)row * 256 + c8];
    else if (c8 < 384) src = &h0[(size_t)row * OUTP + 960 + (c8 - 256)];
    else               src = &h0[(size_t)row * OUTP + 512 + (c8 - 384)];
    float4 a = *reinterpret_cast<const float4*>(src);
    float4 b = *reinterpret_cast<const float4*>(src + 4);
    ushort4* d = reinterpret_cast<ushort4*>(&Acon[(size_t)row * 640 + swz(c8, row)]);
    d[0] = pack4(a); d[1] = pack4(b);
  } else {
    int c8 = (c - 80) * 8;
    float4 a = *reinterpret_cast<const float4*>(&h0[(size_t)row * OUTP + c8]);
    float4 b = *reinterpret_cast<const float4*>(&h0[(size_t)row * OUTP + c8 + 4]);
    ushort4* d = reinterpret_cast<ushort4*>(&Agen[(size_t)row * 576 + swz(64 + c8, row)]);
    d[0] = pack4(a); d[1] = pack4(b);
  }
}

// ---- prep: con weights -> [Wih(384)|Whh(256)], swizzled --------------------
__global__ void packBcon_kernel(const float* __restrict__ wih, const float* __restrict__ whh,
                                ush* __restrict__ B1, ush* __restrict__ B2) {
  int r = blockIdx.x;          // 0..767
  int c4 = threadIdx.x * 4;    // 0..636
  float4 v = (c4 < 384) ? *reinterpret_cast<const float4*>(&wih[(size_t)r * 384 + c4])
                        : *reinterpret_cast<const float4*>(&whh[(size_t)r * 256 + (c4 - 384)]);
  int pc = swz(c4, r);
  ush* dst = (r < 512) ? &B1[(size_t)r * 640 + pc] : &B2[(size_t)(r - 512) * 640 + pc];
  *reinterpret_cast<ushort4*>(dst) = pack4(v);
}

// ---- prep: gen weights -> [Wih(64)|Whh(512)], swizzled ---------------------
__global__ void packBgen_kernel(const float* __restrict__ wih, const float* __restrict__ whh,
                                ush* __restrict__ B1, ush* __restrict__ B2) {
  int r = blockIdx.x;          // 0..1535
  int c4 = threadIdx.x * 4;    // 0..572
  float4 v = (c4 < 64) ? *reinterpret_cast<const float4*>(&wih[(size_t)r * 64 + c4])
                       : *reinterpret_cast<const float4*>(&whh[(size_t)r * 512 + (c4 - 64)]);
  int pc = swz(c4, r);
  ush* dst = (r < 1024) ? &B1[(size_t)r * 576 + pc] : &B2[(size_t)(r - 1024) * 576 + pc];
  *reinterpret_cast<ushort4*>(dst) = pack4(v);
}

// ---- prep: co_W f32->bf16, swizzled (128x256) ------------------------------
__global__ void cvtco_kernel(const float* __restrict__ src, ush* __restrict__ dst) {
  int i = blockIdx.x * 256 + threadIdx.x;      // 128*64
  int row = i >> 6, c4 = (i & 63) * 4;
  float4 v = *reinterpret_cast<const float4*>(&src[(size_t)row * 256 + c4]);
  *reinterpret_cast<ushort4*>(&dst[(size_t)row * 256 + swz(c4, row)]) = pack4(v);
}

// ---- prep: row-L2-normalize fac_W (128x512) -> bf16, swizzled --------------
__global__ void facnorm_kernel(const float* __restrict__ w, ush* __restrict__ dst) {
  int row = blockIdx.x;       // 128
  int lane = threadIdx.x;     // 64
  float v[8]; float s = 0.f;
  #pragma unroll
  for (int i = 0; i < 8; ++i) { v[i] = w[row * 512 + lane * 8 + i]; s += v[i] * v[i]; }
  #pragma unroll
  for (int off = 32; off; off >>= 1) s += __shfl_xor(s, off);
  float scale = 1.f / fmaxf(sqrtf(s), 1e-12f);
  int pc = swz(lane * 8, row);
  #pragma unroll
  for (int i = 0; i < 8; ++i) dst[row * 512 + pc + i] = f2bf(v[i] * scale);
}

// ---- rsample: gi = mean + std*eps -> out + A_gen (swizzled) ----------------
__global__ void rsample_kernel(const float* __restrict__ eps, float* __restrict__ out,
                               ush* __restrict__ Agen) {
  int t = blockIdx.x * 256 + threadIdx.x;      // 32768*64
  int m = t >> 6, j = t & 63;
  float mean = out[(size_t)m * OUTP + 768 + j];
  float sd   = out[(size_t)m * OUTP + 832 + j];
  float g = mean + sd * eps[(size_t)m * 64 + j];
  out[(size_t)m * OUTP + 896 + j] = g;
  Agen[(size_t)m * 576 + (j ^ ((m & 7) << 3))] = f2bf(g);
}

// ---- BIG GEMM: 256x256 tile, BK=64, 512 thr / 8 waves, wave = 128x64 -------
// dbuf 2x64KB, counted vmcnt(8), 2 barriers/K-tile. 64 MFMA vs 24 ds_reads
// per wave per tile (0.375 reads/MFMA). EPI 0 = zr-gate, 1 = n-gate.
template<int EPI, int KTOT, int KA1, int SA1, int SA2, int SB,
         int NT, int NHALF, int SAH, int OOFS, int SHN>
__global__ __launch_bounds__(512, 1) void gemmM_kernel(
    const ush* __restrict__ A1, const ush* __restrict__ A2,
    const ush* __restrict__ B,
    const float* __restrict__ bih, const float* __restrict__ bhh,
    const ush* __restrict__ Ah,
    const ush* __restrict__ zbuf,
    ush* __restrict__ st1, ush* __restrict__ st2,
    float* __restrict__ out)
{
  __shared__ __align__(16) ush S[2 * 32768];   // 128 KB: [buf][A 32KB | B 32KB]
  const int nwg = gridDim.x;
  const int wg = (blockIdx.x & 7) * (nwg >> 3) + (blockIdx.x >> 3);  // XCD-chunked
  const int mt = wg / NT, nt = wg % NT;
  const int m0 = mt * 256, n0 = nt * 256;
  const int tid = threadIdx.x;
  const int wv = tid >> 6, lane = tid & 63;
  const int ln = lane & 15, lk = lane >> 4;
  const int wm = wv >> 2, wn = wv & 3;       // 2M x 4N, wave = 128x64
  const int srow = lane >> 3;
  const int scol = (lane & 7) * 8;
  const int xs = (ln & 7) << 3;
  const int NK = KTOT / 64;

  f32x4 acc[8][4] = {};

  auto STAGE = [&](int t, int b) {
    const int k0 = t * 64;
    ush* As = &S[b * 32768];
    ush* Bs = As + 16384;
    const ush* Ab; size_t sa; int kk;
    if (KA1 >= KTOT || k0 < KA1) { Ab = A1; sa = SA1; kk = k0; }
    else                         { Ab = A2; sa = SA2; kk = k0 - KA1; }
    #pragma unroll
    for (int l = 0; l < 4; ++l) {
      int r0 = l * 64 + wv * 8;
      gld16(Ab + (size_t)(m0 + r0 + srow) * sa + kk + scol, &As[r0 * 64]);
    }
    #pragma unroll
    for (int l = 0; l < 4; ++l) {
      int r0 = l * 64 + wv * 8;
      gld16(B + (size_t)(n0 + r0 + srow) * SB + k0 + scol, &Bs[r0 * 64]);
    }
  };

  STAGE(0, 0);
  for (int t = 0; t < NK; ++t) {
    if (t + 1 < NK) {
      STAGE(t + 1, (t + 1) & 1);
      asm volatile("s_waitcnt vmcnt(8)" ::: "memory");   // tile t landed
    } else {
      asm volatile("s_waitcnt vmcnt(0)" ::: "memory");
    }
    __builtin_amdgcn_s_barrier();
    const ush* As = &S[(t & 1) * 32768];
    const ush* Bs = As + 16384;
    __builtin_amdgcn_s_setprio(1);
    #pragma unroll
    for (int kk2 = 0; kk2 < 2; ++kk2) {
      const int kb = (kk2 * 32 + lk * 8) ^ xs;
      s16x8 af[8], bf[4];
      #pragma unroll
      for (int i = 0; i < 8; ++i) af[i] = ldb8(&As[(wm * 128 + i * 16 + ln) * 64 + kb]);
      #pragma unroll
      for (int j = 0; j < 4; ++j) bf[j] = ldb8(&Bs[(wn * 64 + j * 16 + ln) * 64 + kb]);
      #pragma unroll
      for (int i = 0; i < 8; ++i)
        #pragma unroll
        for (int j = 0; j < 4; ++j)
          acc[i][j] = mfma16(af[i], bf[j], acc[i][j]);
    }
    __builtin_amdgcn_s_setprio(0);
    asm volatile("s_waitcnt lgkmcnt(0)" ::: "memory");   // reads done before re-stage
    __builtin_amdgcn_s_barrier();
  }

  // ---- epilogue via 256x256 bf16 LDS tile (coalesced dumps) ----------------
  ush* Ls = S;   // 128 KB, exactly fits

  if constexpr (EPI == 0) {          // z | r gates
    const bool isz = (n0 < NHALF);
    #pragma unroll
    for (int i = 0; i < 8; ++i) {
      #pragma unroll
      for (int j = 0; j < 4; ++j) {
        const int jl = wn * 64 + j * 16 + ln;
        const int jg = n0 + jl;
        const float bb = bih[jg] + bhh[jg];
        #pragma unroll
        for (int r = 0; r < 4; ++r) {
          const int rl = wm * 128 + i * 16 + lk * 4 + r;
          float sv = sigm(acc[i][j][r] + bb);
          if (!isz) sv *= bf2f(Ah[(size_t)(m0 + rl) * SAH + swz(jg - NHALF, rl)]);
          Ls[rl * 256 + (jl ^ ((rl & 7) << 3))] = f2bf(sv);
        }
      }
    }
    __syncthreads();
    #pragma unroll
    for (int q = 0; q < 16; ++q) {
      int idx = q * 512 + tid;
      int r = idx >> 5, c8 = (idx & 31) * 8;
      float4 v = *reinterpret_cast<const float4*>(&Ls[r * 256 + (c8 ^ ((r & 7) << 3))]);
      if (isz) *reinterpret_cast<float4*>(&st1[(size_t)(m0 + r) * NHALF + n0 + c8]) = v;
      else     *reinterpret_cast<float4*>(&st2[(size_t)(m0 + r) * NHALF +
                                               swz(n0 - NHALF + c8, r)]) = v;
    }
  } else {                           // n gate + combine
    #pragma unroll
    for (int i = 0; i < 8; ++i) {
      #pragma unroll
      for (int j = 0; j < 4; ++j) {
        const int jl = wn * 64 + j * 16 + ln;
        const int jg = n0 + jl;
        const float bb = bih[2 * NHALF + jg] + bhh[2 * NHALF + jg];
        #pragma unroll
        for (int r = 0; r < 4; ++r) {
          const int rl = wm * 128 + i * 16 + lk * 4 + r;
          const size_t m = (size_t)(m0 + rl);
          float n = tanh_(acc[i][j][r] + bb);
          float z = bf2f(zbuf[m * NHALF + jg]);
          float h = bf2f(Ah[m * SAH + swz(jg, rl)]);
          float hv = fminf(fmaxf(z * h + (1.f - z) * n, -5.f), 5.f);
          Ls[rl * 256 + (jl ^ ((rl & 7) << 3))] = f2bf(hv);
        }
      }
    }
    __syncthreads();
    #pragma unroll
    for (int q = 0; q < 16; ++q) {
      int idx = q * 512 + tid;
      int r = idx >> 5, c8 = (idx & 31) * 8;
      union { float4 f; ush u[8]; } U;
      U.f = *reinterpret_cast<const float4*>(&Ls[r * 256 + (c8 ^ ((r & 7) << 3))]);
      *reinterpret_cast<float4*>(&st1[(size_t)(m0 + r) * SHN + swz(n0 + c8, r)]) = U.f;
      float4 o0 = { bf2f(U.u[0]), bf2f(U.u[1]), bf2f(U.u[2]), bf2f(U.u[3]) };
      float4 o1 = { bf2f(U.u[4]), bf2f(U.u[5]), bf2f(U.u[6]), bf2f(U.u[7]) };
      float* ob = &out[(size_t)(m0 + r) * OUTP + OOFS + n0 + c8];
      *reinterpret_cast<float4*>(ob) = o0;
      *reinterpret_cast<float4*>(ob + 4) = o1;
    }
  }
}

// ---- NARROW GEMM (v6): 128x128, 256 thr, single-buf; EPI 2=co, 3=factor ----
template<int EPI, int KTOT, int KA1, int SA1, int SA2, int SB,
         int NT, int NHALF, int SAH, int OOFS, int SHN>
__global__ __launch_bounds__(256, 4) void gemm_kernel(
    const ush* __restrict__ A1, const ush* __restrict__ A2,
    const ush* __restrict__ B,
    const float* __restrict__ bih, const float* __restrict__ bhh,
    const ush* __restrict__ Ah,
    const ush* __restrict__ zbuf,
    ush* __restrict__ st1, ush* __restrict__ st2,
    float* __restrict__ out)
{
  __shared__ ush S[2 * 128 * 64];   // As | Bs (32 KB)
  const int nwg = gridDim.x;
  const int wg = (blockIdx.x & 7) * (nwg >> 3) + (blockIdx.x >> 3);
  const int mt = wg / NT, nt = wg % NT;
  const int m0 = mt * 128, n0 = nt * 128;
  const int tid = threadIdx.x;
  const int w = tid >> 6, lane = tid & 63;
  const int ln = lane & 15, lk = lane >> 4;
  const int wm = w >> 1, wn = w & 1;
  const int srow = lane >> 3;
  const int scol = (lane & 7) * 8;
  const int NK = KTOT / 64;
  const int xs = (ln & 7) << 3;

  f32x4 acc[4][4] = {};
  ush* As = S;
  ush* Bs = S + 8192;

  for (int ks = 0; ks < NK; ++ks) {
    const int k0 = ks * 64;
    const ush* Ab; size_t sa; int kk;
    if (KA1 >= KTOT || k0 < KA1) { Ab = A1; sa = SA1; kk = k0; }
    else                         { Ab = A2; sa = SA2; kk = k0 - KA1; }
    #pragma unroll
    for (int p = 0; p < 4; ++p) {
      int r0 = p * 32 + w * 8;
      gld16(Ab + (size_t)(m0 + r0 + srow) * sa + kk + scol, &As[r0 * 64]);
    }
    #pragma unroll
    for (int p = 0; p < 4; ++p) {
      int r0 = p * 32 + w * 8;
      gld16(B + (size_t)(n0 + r0 + srow) * SB + k0 + scol, &Bs[r0 * 64]);
    }
    asm volatile("s_waitcnt vmcnt(0)" ::: "memory");
    __syncthreads();
    #pragma unroll
    for (int kk2 = 0; kk2 < 2; ++kk2) {
      const int kb = (kk2 * 32 + lk * 8) ^ xs;
      s16x8 af[4], bf[4];
      #pragma unroll
      for (int i = 0; i < 4; ++i) af[i] = ldb8(&As[(wm * 64 + i * 16 + ln) * 64 + kb]);
      #pragma unroll
      for (int i = 0; i < 4; ++i) bf[i] = ldb8(&Bs[(wn * 64 + i * 16 + ln) * 64 + kb]);
      #pragma unroll
      for (int i = 0; i < 4; ++i)
        #pragma unroll
        for (int j = 0; j < 4; ++j)
          acc[i][j] = mfma16(af[i], bf[j], acc[i][j]);
    }
    __syncthreads();
  }

  if constexpr (EPI == 2) {   // co: mean | logvar->std
    #pragma unroll
    for (int i = 0; i < 4; ++i) {
      #pragma unroll
      for (int j = 0; j < 4; ++j) {
        const int jg = n0 + wn * 64 + j * 16 + ln;
        const float bb = bih[jg];
        #pragma unroll
        for (int r = 0; r < 4; ++r) {
          const size_t m = (size_t)(m0 + wm * 64 + i * 16 + lk * 4 + r);
          float v = acc[i][j][r] + bb;
          if (jg < 64) out[m * OUTP + 768 + jg] = v;
          else         out[m * OUTP + 832 + (jg - 64)] = __expf(0.5f * v);
        }
      }
    }
  } else {                    // factor
    #pragma unroll
    for (int i = 0; i < 4; ++i)
      #pragma unroll
      for (int j = 0; j < 4; ++j) {
        const int jg = n0 + wn * 64 + j * 16 + ln;
        #pragma unroll
        for (int r = 0; r < 4; ++r)
          out[(size_t)(m0 + wm * 64 + i * 16 + lk * 4 + r) * OUTP + 960 + jg] =
              acc[i][j][r];
      }
  }
}

extern "C" void kernel_launch(void* const* d_in, const int* in_sizes, int n_in,
                              void* d_out, int out_size, void* d_ws, size_t ws_size,
                              hipStream_t stream) {
  const float* input   = (const float*)d_in[0];
  const float* h0      = (const float*)d_in[1];
  const float* eps     = (const float*)d_in[2];
  const float* gen_Wih = (const float*)d_in[3];
  const float* gen_bih = (const float*)d_in[4];
  const float* gen_Whh = (const float*)d_in[5];
  const float* gen_bhh = (const float*)d_in[6];
  const float* con_Wih = (const float*)d_in[7];
  const float* con_bih = (const float*)d_in[8];
  const float* con_Whh = (const float*)d_in[9];
  const float* con_bhh = (const float*)d_in[10];
  const float* fac_W   = (const float*)d_in[11];
  const float* co_W    = (const float*)d_in[12];
  const float* co_b    = (const float*)d_in[13];
  float* out = (float*)d_out;

  ush* ws = (ush*)d_ws;
  ush* A_gen  = ws;                                  // 32768*576
  ush* A_con  = A_gen + (size_t)NROW * 576;          // 32768*640
  ush* z_con  = A_con + (size_t)NROW * 640;          // 32768*256
  ush* rh_con = z_con + (size_t)NROW * 256;          // 32768*256
  ush* B1c    = rh_con + (size_t)NROW * 256;         // 512*640
  ush* B2c    = B1c + 512 * 640;                     // 256*640
  ush* B1g    = B2c + 256 * 640;                     // 1024*576
  ush* B2g    = B1g + 1024 * 576;                    // 512*576
  ush* coWb   = B2g + 512 * 576;                     // 128*256
  ush* facWn  = coWb + 128 * 256;                    // 128*512
  // aliases over dead con-phase buffers (gen phase runs after co/rsample):
  ush* z_gen  = A_con;                               // 32768*512 <= A_con
  ush* rh_gen = z_con;                               // 32768*512 == z_con+rh_con

  // ---- prep ----
  packBcon_kernel<<<768, 160, 0, stream>>>(con_Wih, con_Whh, B1c, B2c);
  packBgen_kernel<<<1536, 144, 0, stream>>>(gen_Wih, gen_Whh, B1g, B2g);
  cvtco_kernel<<<32, 256, 0, stream>>>(co_W, coWb);
  facnorm_kernel<<<128, 64, 0, stream>>>(fac_W, facWn);
  prepA_kernel<<<18432, 256, 0, stream>>>(input, h0, A_con, A_gen);

  // ---- controller: z,r -> rh ; n -> h_new ; co ; rsample ----
  gemmM_kernel<0, 640, 640, 640, 640, 640, 2, 256, 640, 0, 0>
      <<<256, 512, 0, stream>>>(A_con, A_con, B1c, con_bih, con_bhh,
                                A_con + 384, nullptr, z_con, rh_con, out);
  gemmM_kernel<1, 640, 384, 640, 256, 640, 1, 256, 640, 512, 640>
      <<<128, 512, 0, stream>>>(A_con, rh_con, B2c, con_bih, con_bhh,
                                A_con + 384, z_con, A_con + 384, nullptr, out);
  gemm_kernel<2, 256, 256, 640, 640, 256, 1, 64, 640, 0, 0>
      <<<256, 256, 0, stream>>>(A_con + 384, A_con + 384, coWb, co_b, co_b,
                                nullptr, nullptr, nullptr, nullptr, out);
  rsample_kernel<<<8192, 256, 0, stream>>>(eps, out, A_gen);

  // ---- generator: z,r -> rh ; n -> h_new ; factor ----
  gemmM_kernel<0, 576, 576, 576, 576, 576, 4, 512, 576, 0, 0>
      <<<512, 512, 0, stream>>>(A_gen, A_gen, B1g, gen_bih, gen_bhh,
                                A_gen + 64, nullptr, z_gen, rh_gen, out);
  gemmM_kernel<1, 576, 64, 576, 512, 576, 2, 512, 576, 0, 576>
      <<<256, 512, 0, stream>>>(A_gen, rh_gen, B2g, gen_bih, gen_bhh,
                                A_gen + 64, z_gen, A_gen + 64, nullptr, out);
  gemm_kernel<3, 512, 512, 576, 576, 512, 1, 0, 576, 960, 0>
      <<<256, 256, 0, stream>>>(A_gen + 64, A_gen + 64, facWn, gen_bih, gen_bhh,
                                nullptr, nullptr, nullptr, nullptr, out);
}

// Round 13
// 291.476 us; speedup vs baseline: 4.5482x; 1.8885x over previous
//
#include <hip/hip_runtime.h>

// DecoderCell v13 = v9 (the measured best: dbuf BK=64, counted vmcnt(4)/(8),
// both-sides XOR swizzle, raw s_barrier, setprio, 128x128 tile, 8 waves of
// 64x32, 2 blocks/CU) + FULLY UNROLLED K-loops: NK is constexpr, so the
// A1/A2 switch, buffer parity, and all k0 staging offsets become
// compile-time (addresses fold into instruction offsets) -> cuts the
// VALU address arithmetic that measured at 2x MfmaUtil.
//
// h_0 layout: [gen 0:512 | con 512:768 | mean 768:832 | std 832:896 | gi 896:960 | factor 960:1088]
// A_con[32768][640] = [input 256 | factor 128 | h_con->hnew_con 256]  (swizzled)
// A_gen[32768][576] = [gi 64 | h_gen->hnew_gen 512]                   (swizzled)

typedef short  s16x8 __attribute__((ext_vector_type(8)));
typedef float  f32x4 __attribute__((ext_vector_type(4)));
typedef unsigned short ush;

#define OUTP 1088
#define NROW 32768

__device__ __forceinline__ int swz(int k, int row) {
  return (k & ~63) | ((k & 63) ^ ((row & 7) << 3));
}
__device__ __forceinline__ ush f2bf(float f) {
  union { float f; unsigned int u; } v; v.f = f;
  unsigned int u = v.u;
  return (ush)((u + 0x7FFFu + ((u >> 16) & 1u)) >> 16);  // RNE
}
__device__ __forceinline__ float bf2f(ush b) {
  union { unsigned int u; float f; } v; v.u = ((unsigned int)b) << 16;
  return v.f;
}
__device__ __forceinline__ float sigm(float x) { return 1.f / (1.f + __expf(-x)); }
__device__ __forceinline__ float tanh_(float x) { return 2.f / (1.f + __expf(-2.f * x)) - 1.f; }

__device__ __forceinline__ f32x4 mfma16(s16x8 a, s16x8 b, f32x4 c) {
  return __builtin_amdgcn_mfma_f32_16x16x32_bf16(a, b, c, 0, 0, 0);
}
__device__ __forceinline__ s16x8 ldb8(const ush* p) {
  return *reinterpret_cast<const s16x8*>(p);
}
__device__ __forceinline__ void gld16(const ush* g, ush* l) {
  __builtin_amdgcn_global_load_lds(
      (const __attribute__((address_space(1))) unsigned int*)g,
      (__attribute__((address_space(3))) unsigned int*)l, 16, 0, 0);
}
__device__ __forceinline__ ushort4 pack4(float4 a) {
  ushort4 o; o.x = f2bf(a.x); o.y = f2bf(a.y); o.z = f2bf(a.z); o.w = f2bf(a.w);
  return o;
}

// ---- prep: A_con = [input|factor|h_con] + A_gen h-section, bf16 swizzled ---
__global__ void prepA_kernel(const float* __restrict__ in, const float* __restrict__ h0,
                             ush* __restrict__ Acon, ush* __restrict__ Agen) {
  int t = blockIdx.x * 256 + threadIdx.x;      // 32768 * 144
  int row = t / 144, c = t % 144;
  if (c < 80) {
    int c8 = c * 8;
    const float* src;
    if (c8 < 256)      src = &in[(size_t)row * 256 + c8];
    else if (c8 < 384) src = &h0[(size_t)row * OUTP + 960 + (c8 - 256)];
    else               src = &h0[(size_t)row * OUTP + 512 + (c8 - 384)];
    float4 a = *reinterpret_cast<const float4*>(src);
    float4 b = *reinterpret_cast<const float4*>(src + 4);
    ushort4* d = reinterpret_cast<ushort4*>(&Acon[(size_t)row * 640 + swz(c8, row)]);
    d[0] = pack4(a); d[1] = pack4(b);
  } else {
    int c8 = (c - 80) * 8;
    float4 a = *reinterpret_cast<const float4*>(&h0[(size_t)row * OUTP + c8]);
    float4 b = *reinterpret_cast<const float4*>(&h0[(size_t)row * OUTP + c8 + 4]);
    ushort4* d = reinterpret_cast<ushort4*>(&Agen[(size_t)row * 576 + swz(64 + c8, row)]);
    d[0] = pack4(a); d[1] = pack4(b);
  }
}

// ---- prep: con weights -> [Wih(384)|Whh(256)], swizzled --------------------
__global__ void packBcon_kernel(const float* __restrict__ wih, const float* __restrict__ whh,
                                ush* __restrict__ B1, ush* __restrict__ B2) {
  int r = blockIdx.x;          // 0..767
  int c4 = threadIdx.x * 4;    // 0..636
  float4 v = (c4 < 384) ? *reinterpret_cast<const float4*>(&wih[(size_t)r * 384 + c4])
                        : *reinterpret_cast<const float4*>(&whh[(size_t)r * 256 + (c4 - 384)]);
  int pc = swz(c4, r);
  ush* dst = (r < 512) ? &B1[(size_t)r * 640 + pc] : &B2[(size_t)(r - 512) * 640 + pc];
  *reinterpret_cast<ushort4*>(dst) = pack4(v);
}

// ---- prep: gen weights -> [Wih(64)|Whh(512)], swizzled ---------------------
__global__ void packBgen_kernel(const float* __restrict__ wih, const float* __restrict__ whh,
                                ush* __restrict__ B1, ush* __restrict__ B2) {
  int r = blockIdx.x;          // 0..1535
  int c4 = threadIdx.x * 4;    // 0..572
  float4 v = (c4 < 64) ? *reinterpret_cast<const float4*>(&wih[(size_t)r * 64 + c4])
                       : *reinterpret_cast<const float4*>(&whh[(size_t)r * 512 + (c4 - 64)]);
  int pc = swz(c4, r);
  ush* dst = (r < 1024) ? &B1[(size_t)r * 576 + pc] : &B2[(size_t)(r - 1024) * 576 + pc];
  *reinterpret_cast<ushort4*>(dst) = pack4(v);
}

// ---- prep: co_W f32->bf16, swizzled (128x256) ------------------------------
__global__ void cvtco_kernel(const float* __restrict__ src, ush* __restrict__ dst) {
  int i = blockIdx.x * 256 + threadIdx.x;      // 128*64
  int row = i >> 6, c4 = (i & 63) * 4;
  float4 v = *reinterpret_cast<const float4*>(&src[(size_t)row * 256 + c4]);
  *reinterpret_cast<ushort4*>(&dst[(size_t)row * 256 + swz(c4, row)]) = pack4(v);
}

// ---- prep: row-L2-normalize fac_W (128x512) -> bf16, swizzled --------------
__global__ void facnorm_kernel(const float* __restrict__ w, ush* __restrict__ dst) {
  int row = blockIdx.x;       // 128
  int lane = threadIdx.x;     // 64
  float v[8]; float s = 0.f;
  #pragma unroll
  for (int i = 0; i < 8; ++i) { v[i] = w[row * 512 + lane * 8 + i]; s += v[i] * v[i]; }
  #pragma unroll
  for (int off = 32; off; off >>= 1) s += __shfl_xor(s, off);
  float scale = 1.f / fmaxf(sqrtf(s), 1e-12f);
  int pc = swz(lane * 8, row);
  #pragma unroll
  for (int i = 0; i < 8; ++i) dst[row * 512 + pc + i] = f2bf(v[i] * scale);
}

// ---- rsample: gi = mean + std*eps -> out + A_gen (swizzled) ----------------
__global__ void rsample_kernel(const float* __restrict__ eps, float* __restrict__ out,
                               ush* __restrict__ Agen) {
  int t = blockIdx.x * 256 + threadIdx.x;      // 32768*64
  int m = t >> 6, j = t & 63;
  float mean = out[(size_t)m * OUTP + 768 + j];
  float sd   = out[(size_t)m * OUTP + 832 + j];
  float g = mean + sd * eps[(size_t)m * 64 + j];
  out[(size_t)m * OUTP + 896 + j] = g;
  Agen[(size_t)m * 576 + (j ^ ((m & 7) << 3))] = f2bf(g);
}

// ---- DBUF GEMM: 128x128 tile, BK=64, 512 thr / 8 waves (2M x 4N), UNROLLED -
// Double-buffered LDS (2x32KB), counted vmcnt(4). K-loop fully unrolled:
// all staging offsets & buffer parity compile-time. EPI: 0 = zr, 1 = n.
template<int EPI, int KTOT, int KA1, int SA1, int SA2, int SB,
         int NT, int NHALF, int SAH, int OOFS, int SHN>
__global__ __launch_bounds__(512, 2) void gemmD_kernel(
    const ush* __restrict__ A1, const ush* __restrict__ A2,
    const ush* __restrict__ B,
    const float* __restrict__ bih, const float* __restrict__ bhh,
    const ush* __restrict__ Ah,
    const ush* __restrict__ zbuf,
    ush* __restrict__ st1, ush* __restrict__ st2,
    float* __restrict__ out)
{
  __shared__ __align__(16) ush S[2 * 2 * 128 * 64];   // [buf][A|B], 64 KB
  const int nwg = gridDim.x;
  const int wg = (blockIdx.x & 7) * (nwg >> 3) + (blockIdx.x >> 3);  // XCD-chunked
  const int mt = wg / NT, nt = wg % NT;
  const int m0 = mt * 128, n0 = nt * 128;
  const int tid = threadIdx.x;
  const int wv = tid >> 6, lane = tid & 63;
  const int ln = lane & 15, lk = lane >> 4;
  const int wm = wv >> 2, wn = wv & 3;       // 2 M-halves x 4 N-quarters, 64x32/wave
  const int srow = lane >> 3;
  const int scol = (lane & 7) * 8;
  const int xs = (ln & 7) << 3;
  constexpr int NK = KTOT / 64;

  f32x4 acc[4][2] = {};

  // hoisted per-thread staging bases (k0 added as compile-time constant)
  const int ar0 = wv * 16 + srow, ar1 = wv * 16 + 8 + srow;
  const ush* a1p0 = A1 + (size_t)(m0 + ar0) * SA1 + scol;
  const ush* a1p1 = A1 + (size_t)(m0 + ar1) * SA1 + scol;
  const ush* a2p0 = A2 + (size_t)(m0 + ar0) * SA2 + scol;
  const ush* a2p1 = A2 + (size_t)(m0 + ar1) * SA2 + scol;
  const ush* bp0  = B  + (size_t)(n0 + ar0) * SB  + scol;
  const ush* bp1  = B  + (size_t)(n0 + ar1) * SB  + scol;
  ush* ldsA0 = &S[(wv * 16) * 64];
  ush* ldsA1 = &S[(wv * 16 + 8) * 64];

  auto STAGE = [&](int t, int b) {   // t, b compile-time after unroll
    const int k0 = t * 64;
    ush* As = ldsA0 + b * 16384;
    ush* As1 = ldsA1 + b * 16384;
    if (KA1 >= KTOT || k0 < KA1) {
      gld16(a1p0 + k0, As);
      gld16(a1p1 + k0, As1);
    } else {
      gld16(a2p0 + (k0 - KA1), As);
      gld16(a2p1 + (k0 - KA1), As1);
    }
    gld16(bp0 + k0, As + 8192);
    gld16(bp1 + k0, As1 + 8192);
  };

  STAGE(0, 0);
  #pragma unroll
  for (int t = 0; t < NK; ++t) {
    if (t + 1 < NK) {
      STAGE(t + 1, (t + 1) & 1);
      asm volatile("s_waitcnt vmcnt(4)" ::: "memory");   // stage(t) landed
    } else {
      asm volatile("s_waitcnt vmcnt(0)" ::: "memory");
    }
    __builtin_amdgcn_s_barrier();
    const ush* As = &S[(t & 1) * 16384];
    const ush* Bs = As + 8192;
    __builtin_amdgcn_s_setprio(1);
    #pragma unroll
    for (int kk2 = 0; kk2 < 2; ++kk2) {
      const int kb = (kk2 * 32 + lk * 8) ^ xs;
      s16x8 af[4], bf[2];
      #pragma unroll
      for (int i = 0; i < 4; ++i) af[i] = ldb8(&As[(wm * 64 + i * 16 + ln) * 64 + kb]);
      #pragma unroll
      for (int j = 0; j < 2; ++j) bf[j] = ldb8(&Bs[(wn * 32 + j * 16 + ln) * 64 + kb]);
      #pragma unroll
      for (int i = 0; i < 4; ++i)
        #pragma unroll
        for (int j = 0; j < 2; ++j)
          acc[i][j] = mfma16(af[i], bf[j], acc[i][j]);
    }
    __builtin_amdgcn_s_setprio(0);
    asm volatile("s_waitcnt lgkmcnt(0)" ::: "memory");   // buf free before re-stage
    __builtin_amdgcn_s_barrier();
  }

  // ---- epilogue via 128x128 bf16 LDS tile (coalesced dumps) ----------------
  ush* Ls = S;

  if constexpr (EPI == 0) {          // z | r gates
    const bool isz = (n0 < NHALF);
    #pragma unroll
    for (int i = 0; i < 4; ++i) {
      #pragma unroll
      for (int j = 0; j < 2; ++j) {
        const int jl = wn * 32 + j * 16 + ln;
        const int jg = n0 + jl;
        const float bb = bih[jg] + bhh[jg];
        #pragma unroll
        for (int r = 0; r < 4; ++r) {
          const int rl = wm * 64 + i * 16 + lk * 4 + r;
          float sv = sigm(acc[i][j][r] + bb);
          if (!isz) sv *= bf2f(Ah[(size_t)(m0 + rl) * SAH + swz(jg - NHALF, rl)]);
          Ls[rl * 128 + (jl ^ ((rl & 7) << 3))] = f2bf(sv);
        }
      }
    }
    __syncthreads();
    #pragma unroll
    for (int q = 0; q < 4; ++q) {
      int idx = q * 512 + tid;
      int r = idx >> 4, c8 = (idx & 15) * 8;
      float4 v = *reinterpret_cast<const float4*>(&Ls[r * 128 + (c8 ^ ((r & 7) << 3))]);
      if (isz) *reinterpret_cast<float4*>(&st1[(size_t)(m0 + r) * NHALF + n0 + c8]) = v;
      else     *reinterpret_cast<float4*>(&st2[(size_t)(m0 + r) * NHALF +
                                               swz(n0 - NHALF + c8, r)]) = v;
    }
  } else {                           // n gate + combine
    #pragma unroll
    for (int i = 0; i < 4; ++i) {
      #pragma unroll
      for (int j = 0; j < 2; ++j) {
        const int jl = wn * 32 + j * 16 + ln;
        const int jg = n0 + jl;
        const float bb = bih[2 * NHALF + jg] + bhh[2 * NHALF + jg];
        #pragma unroll
        for (int r = 0; r < 4; ++r) {
          const int rl = wm * 64 + i * 16 + lk * 4 + r;
          const size_t m = (size_t)(m0 + rl);
          float n = tanh_(acc[i][j][r] + bb);
          float z = bf2f(zbuf[m * NHALF + jg]);
          float h = bf2f(Ah[m * SAH + swz(jg, rl)]);
          float hv = fminf(fmaxf(z * h + (1.f - z) * n, -5.f), 5.f);
          Ls[rl * 128 + (jl ^ ((rl & 7) << 3))] = f2bf(hv);
        }
      }
    }
    __syncthreads();
    #pragma unroll
    for (int q = 0; q < 4; ++q) {
      int idx = q * 512 + tid;
      int r = idx >> 4, c8 = (idx & 15) * 8;
      union { float4 f; ush u[8]; } U;
      U.f = *reinterpret_cast<const float4*>(&Ls[r * 128 + (c8 ^ ((r & 7) << 3))]);
      *reinterpret_cast<float4*>(&st1[(size_t)(m0 + r) * SHN + swz(n0 + c8, r)]) = U.f;
      float4 o0 = { bf2f(U.u[0]), bf2f(U.u[1]), bf2f(U.u[2]), bf2f(U.u[3]) };
      float4 o1 = { bf2f(U.u[4]), bf2f(U.u[5]), bf2f(U.u[6]), bf2f(U.u[7]) };
      float* ob = &out[(size_t)(m0 + r) * OUTP + OOFS + n0 + c8];
      *reinterpret_cast<float4*>(ob) = o0;
      *reinterpret_cast<float4*>(ob + 4) = o1;
    }
  }
}

// ---- NARROW GEMM: 128x128, 256 thr, single-buf, UNROLLED; EPI 2=co, 3=fac --
template<int EPI, int KTOT, int KA1, int SA1, int SA2, int SB,
         int NT, int NHALF, int SAH, int OOFS, int SHN>
__global__ __launch_bounds__(256, 4) void gemm_kernel(
    const ush* __restrict__ A1, const ush* __restrict__ A2,
    const ush* __restrict__ B,
    const float* __restrict__ bih, const float* __restrict__ bhh,
    const ush* __restrict__ Ah,
    const ush* __restrict__ zbuf,
    ush* __restrict__ st1, ush* __restrict__ st2,
    float* __restrict__ out)
{
  __shared__ ush S[2 * 128 * 64];   // As | Bs (32 KB)
  const int nwg = gridDim.x;
  const int wg = (blockIdx.x & 7) * (nwg >> 3) + (blockIdx.x >> 3);
  const int mt = wg / NT, nt = wg % NT;
  const int m0 = mt * 128, n0 = nt * 128;
  const int tid = threadIdx.x;
  const int w = tid >> 6, lane = tid & 63;
  const int ln = lane & 15, lk = lane >> 4;
  const int wm = w >> 1, wn = w & 1;
  const int srow = lane >> 3;
  const int scol = (lane & 7) * 8;
  constexpr int NK = KTOT / 64;
  const int xs = (ln & 7) << 3;

  f32x4 acc[4][4] = {};
  ush* As = S;
  ush* Bs = S + 8192;

  #pragma unroll
  for (int ks = 0; ks < NK; ++ks) {
    const int k0 = ks * 64;
    const ush* Ab; size_t sa; int kk;
    if (KA1 >= KTOT || k0 < KA1) { Ab = A1; sa = SA1; kk = k0; }
    else                         { Ab = A2; sa = SA2; kk = k0 - KA1; }
    #pragma unroll
    for (int p = 0; p < 4; ++p) {
      int r0 = p * 32 + w * 8;
      gld16(Ab + (size_t)(m0 + r0 + srow) * sa + kk + scol, &As[r0 * 64]);
    }
    #pragma unroll
    for (int p = 0; p < 4; ++p) {
      int r0 = p * 32 + w * 8;
      gld16(B + (size_t)(n0 + r0 + srow) * SB + k0 + scol, &Bs[r0 * 64]);
    }
    asm volatile("s_waitcnt vmcnt(0)" ::: "memory");
    __syncthreads();
    #pragma unroll
    for (int kk2 = 0; kk2 < 2; ++kk2) {
      const int kb = (kk2 * 32 + lk * 8) ^ xs;
      s16x8 af[4], bf[4];
      #pragma unroll
      for (int i = 0; i < 4; ++i) af[i] = ldb8(&As[(wm * 64 + i * 16 + ln) * 64 + kb]);
      #pragma unroll
      for (int i = 0; i < 4; ++i) bf[i] = ldb8(&Bs[(wn * 64 + i * 16 + ln) * 64 + kb]);
      #pragma unroll
      for (int i = 0; i < 4; ++i)
        #pragma unroll
        for (int j = 0; j < 4; ++j)
          acc[i][j] = mfma16(af[i], bf[j], acc[i][j]);
    }
    __syncthreads();
  }

  if constexpr (EPI == 2) {   // co: mean | logvar->std
    #pragma unroll
    for (int i = 0; i < 4; ++i) {
      #pragma unroll
      for (int j = 0; j < 4; ++j) {
        const int jg = n0 + wn * 64 + j * 16 + ln;
        const float bb = bih[jg];
        #pragma unroll
        for (int r = 0; r < 4; ++r) {
          const size_t m = (size_t)(m0 + wm * 64 + i * 16 + lk * 4 + r);
          float v = acc[i][j][r] + bb;
          if (jg < 64) out[m * OUTP + 768 + jg] = v;
          else         out[m * OUTP + 832 + (jg - 64)] = __expf(0.5f * v);
        }
      }
    }
  } else {                    // factor
    #pragma unroll
    for (int i = 0; i < 4; ++i)
      #pragma unroll
      for (int j = 0; j < 4; ++j) {
        const int jg = n0 + wn * 64 + j * 16 + ln;
        #pragma unroll
        for (int r = 0; r < 4; ++r)
          out[(size_t)(m0 + wm * 64 + i * 16 + lk * 4 + r) * OUTP + 960 + jg] =
              acc[i][j][r];
      }
  }
}

extern "C" void kernel_launch(void* const* d_in, const int* in_sizes, int n_in,
                              void* d_out, int out_size, void* d_ws, size_t ws_size,
                              hipStream_t stream) {
  const float* input   = (const float*)d_in[0];
  const float* h0      = (const float*)d_in[1];
  const float* eps     = (const float*)d_in[2];
  const float* gen_Wih = (const float*)d_in[3];
  const float* gen_bih = (const float*)d_in[4];
  const float* gen_Whh = (const float*)d_in[5];
  const float* gen_bhh = (const float*)d_in[6];
  const float* con_Wih = (const float*)d_in[7];
  const float* con_bih = (const float*)d_in[8];
  const float* con_Whh = (const float*)d_in[9];
  const float* con_bhh = (const float*)d_in[10];
  const float* fac_W   = (const float*)d_in[11];
  const float* co_W    = (const float*)d_in[12];
  const float* co_b    = (const float*)d_in[13];
  float* out = (float*)d_out;

  ush* ws = (ush*)d_ws;
  ush* A_gen  = ws;                                  // 32768*576
  ush* A_con  = A_gen + (size_t)NROW * 576;          // 32768*640
  ush* z_con  = A_con + (size_t)NROW * 640;          // 32768*256
  ush* rh_con = z_con + (size_t)NROW * 256;          // 32768*256
  ush* B1c    = rh_con + (size_t)NROW * 256;         // 512*640
  ush* B2c    = B1c + 512 * 640;                     // 256*640
  ush* B1g    = B2c + 256 * 640;                     // 1024*576
  ush* B2g    = B1g + 1024 * 576;                    // 512*576
  ush* coWb   = B2g + 512 * 576;                     // 128*256
  ush* facWn  = coWb + 128 * 256;                    // 128*512
  // aliases over dead con-phase buffers (gen phase runs after co/rsample):
  ush* z_gen  = A_con;                               // 32768*512 <= A_con
  ush* rh_gen = z_con;                               // 32768*512 == z_con+rh_con

  // ---- prep ----
  packBcon_kernel<<<768, 160, 0, stream>>>(con_Wih, con_Whh, B1c, B2c);
  packBgen_kernel<<<1536, 144, 0, stream>>>(gen_Wih, gen_Whh, B1g, B2g);
  cvtco_kernel<<<32, 256, 0, stream>>>(co_W, coWb);
  facnorm_kernel<<<128, 64, 0, stream>>>(fac_W, facWn);
  prepA_kernel<<<18432, 256, 0, stream>>>(input, h0, A_con, A_gen);

  // ---- controller: z,r -> rh ; n -> h_new ; co ; rsample ----
  gemmD_kernel<0, 640, 640, 640, 640, 640, 4, 256, 640, 0, 0>
      <<<1024, 512, 0, stream>>>(A_con, A_con, B1c, con_bih, con_bhh,
                                 A_con + 384, nullptr, z_con, rh_con, out);
  gemmD_kernel<1, 640, 384, 640, 256, 640, 2, 256, 640, 512, 640>
      <<<512, 512, 0, stream>>>(A_con, rh_con, B2c, con_bih, con_bhh,
                                A_con + 384, z_con, A_con + 384, nullptr, out);
  gemm_kernel<2, 256, 256, 640, 640, 256, 1, 64, 640, 0, 0>
      <<<256, 256, 0, stream>>>(A_con + 384, A_con + 384, coWb, co_b, co_b,
                                nullptr, nullptr, nullptr, nullptr, out);
  rsample_kernel<<<8192, 256, 0, stream>>>(eps, out, A_gen);

  // ---- generator: z,r -> rh ; n -> h_new ; factor ----
  gemmD_kernel<0, 576, 576, 576, 576, 576, 8, 512, 576, 0, 0>
      <<<2048, 512, 0, stream>>>(A_gen, A_gen, B1g, gen_bih, gen_bhh,
                                 A_gen + 64, nullptr, z_gen, rh_gen, out);
  gemmD_kernel<1, 576, 64, 576, 512, 576, 4, 512, 576, 0, 576>
      <<<1024, 512, 0, stream>>>(A_gen, rh_gen, B2g, gen_bih, gen_bhh,
                                 A_gen + 64, z_gen, A_gen + 64, nullptr, out);
  gemm_kernel<3, 512, 512, 576, 576, 512, 1, 0, 576, 960, 0>
      <<<256, 256, 0, stream>>>(A_gen + 64, A_gen + 64, facWn, gen_bih, gen_bhh,
                                nullptr, nullptr, nullptr, nullptr, out);
}